// Round 14
// baseline (386.693 us; speedup 1.0000x reference)
//
#include <hip/hip_runtime.h>
#include <hip/hip_bf16.h>
#include <math.h>

// ---------------------------------------------------------------------------
// GraphSAGE 2-layer forward.
// mean_j(x_j) @ W_r == mean_j(x_j @ W_r) -> project first, aggregate small.
// R14: fused2 gather -> packed-bf16 dual-edge scheme. y1 split: y1l fp32
// (self), y1r packed bf16 rows of 32 u32 (gather). Wave halves process
// even/odd edges; 1 u32 load/lane per 2 edges (half the loads AND bytes of
// R10). shfl_xor(32) combine + shfl redistribute to lane=feature.
// Structurally different codegen from R11's failed scalar-ushort path
// (124 VGPR) and R12's capped spills. agg2 unchanged (one variable).
// ---------------------------------------------------------------------------

typedef __attribute__((ext_vector_type(8))) short bf16x8;
typedef __attribute__((ext_vector_type(4))) float f32x4;

static __device__ __forceinline__ unsigned short f2bf(float f) {
    unsigned int u = __builtin_bit_cast(unsigned int, f);
    unsigned int r = (u + 0x7FFFu + ((u >> 16) & 1u)) >> 16;   // RNE
    return (unsigned short)r;
}
static __device__ __forceinline__ float bf2f(unsigned int lo16) {
    unsigned int v = lo16 << 16;
    return __builtin_bit_cast(float, v);
}

// ---------------- CSR build ----------------

__global__ void k_count(const int* __restrict__ dst, int* __restrict__ cnt, int E) {
    int e = blockIdx.x * blockDim.x + threadIdx.x;
    if (e < E) atomicAdd(&cnt[dst[e]], 1);
}

__global__ void k_blocksum(const int* __restrict__ cnt, int* __restrict__ bsum, int N) {
    __shared__ int sm[256];
    int i = blockIdx.x * 256 + threadIdx.x;
    sm[threadIdx.x] = (i < N) ? cnt[i] : 0;
    __syncthreads();
    for (int s = 128; s > 0; s >>= 1) {
        if (threadIdx.x < s) sm[threadIdx.x] += sm[threadIdx.x + s];
        __syncthreads();
    }
    if (threadIdx.x == 0) bsum[blockIdx.x] = sm[0];
}

__global__ void k_scanbsum(int* __restrict__ bsum, int nb) {
    __shared__ int a[512], b[512];
    int t = threadIdx.x;
    int v = (t < nb) ? bsum[t] : 0;
    a[t] = v;
    __syncthreads();
    int* pin = a; int* pout = b;
    for (int o = 1; o < 512; o <<= 1) {
        pout[t] = (t >= o) ? pin[t] + pin[t - o] : pin[t];
        __syncthreads();
        int* tmp = pin; pin = pout; pout = tmp;
    }
    if (t < nb) bsum[t] = pin[t] - v;   // exclusive
}

__global__ void k_scanfinal(const int* __restrict__ cnt, const int* __restrict__ bsum,
                            int* __restrict__ off, int* __restrict__ cursor, int N) {
    __shared__ int a[256], b[256];
    int t = threadIdx.x;
    int i = blockIdx.x * 256 + t;
    int v = (i < N) ? cnt[i] : 0;
    a[t] = v;
    __syncthreads();
    int* pin = a; int* pout = b;
    for (int o = 1; o < 256; o <<= 1) {
        pout[t] = (t >= o) ? pin[t] + pin[t - o] : pin[t];
        __syncthreads();
        int* tmp = pin; pin = pout; pout = tmp;
    }
    if (i < N) {
        int ex = bsum[blockIdx.x] + pin[t] - v;
        off[i] = ex;
        cursor[i] = ex;
    }
}

// scatter, dst-range partitioned (pass = blockIdx.y): csr window L2-resident
__global__ void k_scatterp(const int* __restrict__ src, const int* __restrict__ dst,
                           int* __restrict__ cursor, int* __restrict__ csr,
                           int E, int range) {
    int e = blockIdx.x * blockDim.x + threadIdx.x;
    if (e < E) {
        int d = dst[e];
        int lo = blockIdx.y * range;
        if (d >= lo && d < lo + range) {
            int pos = atomicAdd(&cursor[d], 1);
            csr[pos] = src[e];
        }
    }
}

// ------- GEMM1 (MFMA): [y1l fp32 | y1r bf16] = bf16(x) @ bf16([W1_l|W1_r]) --

__global__ __launch_bounds__(256) void k_gemm1(const float* __restrict__ x,
                                               const float* __restrict__ Wl,
                                               const float* __restrict__ Wr,
                                               float* __restrict__ y1l,
                                               unsigned short* __restrict__ y1r, int N) {
    __shared__ unsigned short xs[64][40];     // bf16 [row][k]
    __shared__ unsigned short wsm[128][40];   // bf16 [col][k]
    int tid = threadIdx.x;
    int row0 = blockIdx.x * 64;
    int lane = tid & 63;
    int wid = tid >> 6;
    int wm = wid >> 1;
    int wn = wid & 1;

    int xr = tid >> 2;
    int xq = tid & 3;
    int wc = tid >> 1;
    int wo = tid & 1;
    const float* wsrc = (wc < 64) ? (Wl + wc) : (Wr + (wc - 64));

    f32x4 acc[2][4];
    #pragma unroll
    for (int m = 0; m < 2; ++m)
        #pragma unroll
        for (int n = 0; n < 4; ++n) acc[m][n] = (f32x4){0.f, 0.f, 0.f, 0.f};

    for (int kk = 0; kk < 256; kk += 32) {
        {
            int grow = row0 + xr;
            float4 v0 = make_float4(0.f, 0.f, 0.f, 0.f);
            float4 v1 = make_float4(0.f, 0.f, 0.f, 0.f);
            if (grow < N) {
                const float* p = x + (size_t)grow * 256 + kk + xq * 8;
                v0 = *(const float4*)(p);
                v1 = *(const float4*)(p + 4);
            }
            bf16x8 pk;
            pk[0] = (short)f2bf(v0.x); pk[1] = (short)f2bf(v0.y);
            pk[2] = (short)f2bf(v0.z); pk[3] = (short)f2bf(v0.w);
            pk[4] = (short)f2bf(v1.x); pk[5] = (short)f2bf(v1.y);
            pk[6] = (short)f2bf(v1.z); pk[7] = (short)f2bf(v1.w);
            *(bf16x8*)(&xs[xr][xq * 8]) = pk;
        }
        {
            bf16x8 w0, w1;
            #pragma unroll
            for (int j = 0; j < 8; ++j)
                w0[j] = (short)f2bf(wsrc[(size_t)(kk + wo * 16 + j) * 64]);
            #pragma unroll
            for (int j = 0; j < 8; ++j)
                w1[j] = (short)f2bf(wsrc[(size_t)(kk + wo * 16 + 8 + j) * 64]);
            *(bf16x8*)(&wsm[wc][wo * 16])     = w0;
            *(bf16x8*)(&wsm[wc][wo * 16 + 8]) = w1;
        }
        __syncthreads();

        int fr = lane & 15;
        int ko = (lane >> 4) * 8;
        bf16x8 a0 = *(const bf16x8*)(&xs[wm * 32 + fr][ko]);
        bf16x8 a1 = *(const bf16x8*)(&xs[wm * 32 + 16 + fr][ko]);
        bf16x8 b0 = *(const bf16x8*)(&wsm[wn * 64 + fr][ko]);
        bf16x8 b1 = *(const bf16x8*)(&wsm[wn * 64 + 16 + fr][ko]);
        bf16x8 b2 = *(const bf16x8*)(&wsm[wn * 64 + 32 + fr][ko]);
        bf16x8 b3 = *(const bf16x8*)(&wsm[wn * 64 + 48 + fr][ko]);

        acc[0][0] = __builtin_amdgcn_mfma_f32_16x16x32_bf16(a0, b0, acc[0][0], 0, 0, 0);
        acc[0][1] = __builtin_amdgcn_mfma_f32_16x16x32_bf16(a0, b1, acc[0][1], 0, 0, 0);
        acc[0][2] = __builtin_amdgcn_mfma_f32_16x16x32_bf16(a0, b2, acc[0][2], 0, 0, 0);
        acc[0][3] = __builtin_amdgcn_mfma_f32_16x16x32_bf16(a0, b3, acc[0][3], 0, 0, 0);
        acc[1][0] = __builtin_amdgcn_mfma_f32_16x16x32_bf16(a1, b0, acc[1][0], 0, 0, 0);
        acc[1][1] = __builtin_amdgcn_mfma_f32_16x16x32_bf16(a1, b1, acc[1][1], 0, 0, 0);
        acc[1][2] = __builtin_amdgcn_mfma_f32_16x16x32_bf16(a1, b2, acc[1][2], 0, 0, 0);
        acc[1][3] = __builtin_amdgcn_mfma_f32_16x16x32_bf16(a1, b3, acc[1][3], 0, 0, 0);
        __syncthreads();
    }

    // epilogue: C col = lane&15, row = (lane>>4)*4 + r
    // wn==0 -> self cols (fp32 y1l); wn==1 -> neighbor cols (bf16 y1r)
    int cn = lane & 15;
    int r4 = (lane >> 4) * 4;
    #pragma unroll
    for (int m = 0; m < 2; ++m) {
        #pragma unroll
        for (int r = 0; r < 4; ++r) {
            int row = row0 + wm * 32 + m * 16 + r4 + r;
            if (row < N) {
                if (wn == 0) {
                    float* yp = y1l + (size_t)row * 64 + cn;
                    yp[0]  = acc[m][0][r];
                    yp[16] = acc[m][1][r];
                    yp[32] = acc[m][2][r];
                    yp[48] = acc[m][3][r];
                } else {
                    unsigned short* yq = y1r + (size_t)row * 64 + cn;
                    yq[0]  = f2bf(acc[m][0][r]);
                    yq[16] = f2bf(acc[m][1][r]);
                    yq[32] = f2bf(acc[m][2][r]);
                    yq[48] = f2bf(acc[m][3][r]);
                }
            }
        }
    }
}

// ---- Fused: h_i = relu(y1l_i + mean(y1r[nbr]) + b1);  y2_i = h_i @ W2 ------
// Gather: packed bf16 rows (32 u32). Lanes 0-31 even edges, 32-63 odd edges;
// lane holds features {2*fl, 2*fl+1}. Combine via shfl_xor(32) + redistribute.

__global__ __launch_bounds__(256) void k_fused2(const float* __restrict__ y1l,
                                                const unsigned int* __restrict__ y1ru,
                                                const int* __restrict__ csr,
                                                const int* __restrict__ off,
                                                const int* __restrict__ cnt,
                                                const float* __restrict__ b1,
                                                const float* __restrict__ W2l,
                                                const float* __restrict__ W2r,
                                                float* __restrict__ y2, int N) {
    __shared__ float wsm[64][80];    // [k][col], cols 0-39 = W2l, 40-79 = W2r
    __shared__ float hrow[4][64];    // per-wave h_i scratch
    int tid = threadIdx.x;
    #pragma unroll
    for (int it = 0; it < 5; ++it) {
        int idx = tid + it * 256;            // 0..1279
        int k = idx / 20;
        int cq = idx % 20;
        const float* s = (cq < 10) ? (W2l + (size_t)k * 40 + cq * 4)
                                   : (W2r + (size_t)k * 40 + (cq - 10) * 4);
        *(float4*)(&wsm[k][cq * 4]) = *(const float4*)s;
    }
    __syncthreads();

    int lane = tid & 63;
    int half = lane >> 5;            // 0: even edges, 1: odd edges
    int fl = lane & 31;              // feature-pair index (features 2fl, 2fl+1)
    int wv = tid >> 6;
    int wid = blockIdx.x * 4 + wv;
    int nw = gridDim.x * 4;
    float bl = b1[lane];
    int cl = (lane < 40) ? 2 * lane : 0;

    for (int i = wid; i < N; i += nw) {
        int deg = cnt[i];
        int start = off[i];
        float p0 = 0.f, p1 = 0.f;
        for (int base = 0; base < deg; base += 64) {
            int m = min(64, deg - base);
            int s = (lane < m) ? csr[start + base + lane] : 0;
            int pairs = (m + 1) >> 1;
            int t = 0;
            for (; t + 2 <= pairs; t += 2) {    // 4 edges per iter, 2 loads/lane
                int e0 = 2 * t + half;
                int e1 = e0 + 2;
                int s0 = __shfl(s, e0);
                int s1 = __shfl(s, e1);
                unsigned int u0 = y1ru[(size_t)s0 * 32 + fl];
                unsigned int u1 = y1ru[(size_t)s1 * 32 + fl];
                if (e0 < m) { p0 += bf2f(u0 & 0xffffu); p1 += bf2f(u0 >> 16); }
                if (e1 < m) { p0 += bf2f(u1 & 0xffffu); p1 += bf2f(u1 >> 16); }
            }
            for (; t < pairs; ++t) {
                int e0 = 2 * t + half;
                int s0 = __shfl(s, e0);
                unsigned int u0 = y1ru[(size_t)s0 * 32 + fl];
                if (e0 < m) { p0 += bf2f(u0 & 0xffffu); p1 += bf2f(u0 >> 16); }
            }
        }
        // combine even/odd halves, then redistribute to lane=feature
        p0 += __shfl_xor(p0, 32);
        p1 += __shfl_xor(p1, 32);
        float q0 = __shfl(p0, lane >> 1);
        float q1 = __shfl(p1, lane >> 1);
        float sum = (lane & 1) ? q1 : q0;
        float mean = sum / (float)max(deg, 1);
        float hv = fmaxf(y1l[(size_t)i * 64 + lane] + mean + bl, 0.f);

        hrow[wv][lane] = hv;
        float g0 = 0.f, g1 = 0.f;
        #pragma unroll
        for (int k4 = 0; k4 < 64; k4 += 4) {
            float4 hk = *(const float4*)(&hrow[wv][k4]);
            float2 w0 = *(const float2*)(&wsm[k4 + 0][cl]);
            float2 w1 = *(const float2*)(&wsm[k4 + 1][cl]);
            float2 w2 = *(const float2*)(&wsm[k4 + 2][cl]);
            float2 w3 = *(const float2*)(&wsm[k4 + 3][cl]);
            g0 += hk.x * w0.x + hk.y * w1.x + hk.z * w2.x + hk.w * w3.x;
            g1 += hk.x * w0.y + hk.y * w1.y + hk.z * w2.y + hk.w * w3.y;
        }
        if (lane < 40)
            *(float2*)(y2 + (size_t)i * 80 + cl) = make_float2(g0, g1);
    }
}

// ---------------- Agg2 + bias + softmax -------------------------------------

__global__ void k_agg2(const float* __restrict__ y2, const int* __restrict__ csr,
                       const int* __restrict__ off, const int* __restrict__ cnt,
                       const float* __restrict__ b2, float* __restrict__ out, int N) {
    int lane = threadIdx.x & 63;
    int wid = (blockIdx.x * blockDim.x + threadIdx.x) >> 6;
    int nw = (gridDim.x * blockDim.x) >> 6;
    for (int i = wid; i < N; i += nw) {
        int deg = cnt[i];
        int start = off[i];
        float a0 = 0.f, a1 = 0.f, a2 = 0.f, a3 = 0.f;
        bool act = (lane < 40);
        for (int base = 0; base < deg; base += 64) {
            int m = min(64, deg - base);
            int s = (lane < m) ? csr[start + base + lane] : 0;
            int j = 0;
            for (; j + 4 <= m; j += 4) {
                int s0 = __shfl(s, j), s1 = __shfl(s, j + 1);
                int s2 = __shfl(s, j + 2), s3 = __shfl(s, j + 3);
                if (act) {
                    a0 += y2[(size_t)s0 * 80 + 40 + lane];
                    a1 += y2[(size_t)s1 * 80 + 40 + lane];
                    a2 += y2[(size_t)s2 * 80 + 40 + lane];
                    a3 += y2[(size_t)s3 * 80 + 40 + lane];
                }
            }
            for (; j < m; ++j) {
                int sj = __shfl(s, j);
                if (act) a0 += y2[(size_t)sj * 80 + 40 + lane];
            }
        }
        float logit = -INFINITY;
        if (act) {
            float mean = (a0 + a1 + a2 + a3) / (float)max(deg, 1);
            logit = y2[(size_t)i * 80 + lane] + mean + b2[lane];
        }
        float mx = logit;
        #pragma unroll
        for (int o = 32; o > 0; o >>= 1) mx = fmaxf(mx, __shfl_xor(mx, o));
        float e = act ? expf(logit - mx) : 0.f;
        float se = e;
        #pragma unroll
        for (int o = 32; o > 0; o >>= 1) se += __shfl_xor(se, o);
        if (act) out[(size_t)i * 40 + lane] = e / se;
    }
}

// ---------------- launch ----------------------------------------------------

extern "C" void kernel_launch(void* const* d_in, const int* in_sizes, int n_in,
                              void* d_out, int out_size, void* d_ws, size_t ws_size,
                              hipStream_t stream) {
    const float* x   = (const float*)d_in[0];
    const int*   ei  = (const int*)d_in[1];
    const float* W1l = (const float*)d_in[2];
    const float* W1r = (const float*)d_in[3];
    const float* b1  = (const float*)d_in[4];
    const float* W2l = (const float*)d_in[5];
    const float* W2r = (const float*)d_in[6];
    const float* b2  = (const float*)d_in[7];
    float* out = (float*)d_out;

    int N = in_sizes[0] / 256;
    int E = in_sizes[1] / 2;
    const int* srcp = ei;
    const int* dstp = ei + E;

    char* w = (char*)d_ws;
    auto alloc = [&](size_t bytes) {
        char* p = w;
        w += (bytes + 255) & ~(size_t)255;
        return p;
    };
    int nb = (N + 255) / 256;
    int*            cnt    = (int*)alloc((size_t)N * 4);
    int*            off    = (int*)alloc((size_t)N * 4);
    int*            cursor = (int*)alloc((size_t)N * 4);
    int*            bsum   = (int*)alloc((size_t)nb * 4);
    int*            csr    = (int*)alloc((size_t)E * 4);
    float*          y1l    = (float*)alloc((size_t)N * 64 * 4);
    unsigned short* y1r    = (unsigned short*)alloc((size_t)N * 64 * 2);
    float*          y2     = (float*)alloc((size_t)N * 80 * 4);

    hipMemsetAsync(cnt, 0, (size_t)N * 4, stream);
    k_count<<<(E + 255) / 256, 256, 0, stream>>>(dstp, cnt, E);
    k_blocksum<<<nb, 256, 0, stream>>>(cnt, bsum, N);
    k_scanbsum<<<1, 512, 0, stream>>>(bsum, nb);
    k_scanfinal<<<nb, 256, 0, stream>>>(cnt, bsum, off, cursor, N);

    const int P = 4;
    int range = (N + P - 1) / P;               // 25K nodes -> 1.6MB csr window
    dim3 sgrid((E + 255) / 256, P);
    k_scatterp<<<sgrid, 256, 0, stream>>>(srcp, dstp, cursor, csr, E, range);

    k_gemm1<<<(N + 63) / 64, 256, 0, stream>>>(x, W1l, W1r, y1l, y1r, N);
    k_fused2<<<1792, 256, 0, stream>>>(y1l, (const unsigned int*)y1r, csr, off, cnt,
                                       b1, W2l, W2r, y2, N);
    k_agg2<<<2048, 256, 0, stream>>>(y2, csr, off, cnt, b2, out, N);
}

// Round 15
// 374.280 us; speedup vs baseline: 1.0332x; 1.0332x over previous
//
#include <hip/hip_runtime.h>
#include <hip/hip_bf16.h>
#include <math.h>

// ---------------------------------------------------------------------------
// GraphSAGE 2-layer forward.
// mean_j(x_j) @ W_r == mean_j(x_j @ W_r) -> project first, aggregate small.
// R15: fused2 gather is LATENCY-bound, not BW-bound (R14: FETCH halved to
// 99MB yet 13% HBM peak, slower). Keep packed-bf16 dual-edge gather but
// unroll pair-loop x4: 4 independent u32 loads = 8 edges in flight per lane
// (R14 had 2 loads/4 edges; R10 4 loads/4 edges). Same bytes as R14, 2x the
// edges-in-flight of both predecessors. agg2 unchanged.
// ---------------------------------------------------------------------------

typedef __attribute__((ext_vector_type(8))) short bf16x8;
typedef __attribute__((ext_vector_type(4))) float f32x4;

static __device__ __forceinline__ unsigned short f2bf(float f) {
    unsigned int u = __builtin_bit_cast(unsigned int, f);
    unsigned int r = (u + 0x7FFFu + ((u >> 16) & 1u)) >> 16;   // RNE
    return (unsigned short)r;
}
static __device__ __forceinline__ float bf2f(unsigned int lo16) {
    unsigned int v = lo16 << 16;
    return __builtin_bit_cast(float, v);
}

// ---------------- CSR build ----------------

__global__ void k_count(const int* __restrict__ dst, int* __restrict__ cnt, int E) {
    int e = blockIdx.x * blockDim.x + threadIdx.x;
    if (e < E) atomicAdd(&cnt[dst[e]], 1);
}

__global__ void k_blocksum(const int* __restrict__ cnt, int* __restrict__ bsum, int N) {
    __shared__ int sm[256];
    int i = blockIdx.x * 256 + threadIdx.x;
    sm[threadIdx.x] = (i < N) ? cnt[i] : 0;
    __syncthreads();
    for (int s = 128; s > 0; s >>= 1) {
        if (threadIdx.x < s) sm[threadIdx.x] += sm[threadIdx.x + s];
        __syncthreads();
    }
    if (threadIdx.x == 0) bsum[blockIdx.x] = sm[0];
}

__global__ void k_scanbsum(int* __restrict__ bsum, int nb) {
    __shared__ int a[512], b[512];
    int t = threadIdx.x;
    int v = (t < nb) ? bsum[t] : 0;
    a[t] = v;
    __syncthreads();
    int* pin = a; int* pout = b;
    for (int o = 1; o < 512; o <<= 1) {
        pout[t] = (t >= o) ? pin[t] + pin[t - o] : pin[t];
        __syncthreads();
        int* tmp = pin; pin = pout; pout = tmp;
    }
    if (t < nb) bsum[t] = pin[t] - v;   // exclusive
}

__global__ void k_scanfinal(const int* __restrict__ cnt, const int* __restrict__ bsum,
                            int* __restrict__ off, int* __restrict__ cursor, int N) {
    __shared__ int a[256], b[256];
    int t = threadIdx.x;
    int i = blockIdx.x * 256 + t;
    int v = (i < N) ? cnt[i] : 0;
    a[t] = v;
    __syncthreads();
    int* pin = a; int* pout = b;
    for (int o = 1; o < 256; o <<= 1) {
        pout[t] = (t >= o) ? pin[t] + pin[t - o] : pin[t];
        __syncthreads();
        int* tmp = pin; pin = pout; pout = tmp;
    }
    if (i < N) {
        int ex = bsum[blockIdx.x] + pin[t] - v;
        off[i] = ex;
        cursor[i] = ex;
    }
}

// scatter, dst-range partitioned (pass = blockIdx.y): csr window L2-resident
__global__ void k_scatterp(const int* __restrict__ src, const int* __restrict__ dst,
                           int* __restrict__ cursor, int* __restrict__ csr,
                           int E, int range) {
    int e = blockIdx.x * blockDim.x + threadIdx.x;
    if (e < E) {
        int d = dst[e];
        int lo = blockIdx.y * range;
        if (d >= lo && d < lo + range) {
            int pos = atomicAdd(&cursor[d], 1);
            csr[pos] = src[e];
        }
    }
}

// ------- GEMM1 (MFMA): [y1l fp32 | y1r bf16] = bf16(x) @ bf16([W1_l|W1_r]) --

__global__ __launch_bounds__(256) void k_gemm1(const float* __restrict__ x,
                                               const float* __restrict__ Wl,
                                               const float* __restrict__ Wr,
                                               float* __restrict__ y1l,
                                               unsigned short* __restrict__ y1r, int N) {
    __shared__ unsigned short xs[64][40];     // bf16 [row][k]
    __shared__ unsigned short wsm[128][40];   // bf16 [col][k]
    int tid = threadIdx.x;
    int row0 = blockIdx.x * 64;
    int lane = tid & 63;
    int wid = tid >> 6;
    int wm = wid >> 1;
    int wn = wid & 1;

    int xr = tid >> 2;
    int xq = tid & 3;
    int wc = tid >> 1;
    int wo = tid & 1;
    const float* wsrc = (wc < 64) ? (Wl + wc) : (Wr + (wc - 64));

    f32x4 acc[2][4];
    #pragma unroll
    for (int m = 0; m < 2; ++m)
        #pragma unroll
        for (int n = 0; n < 4; ++n) acc[m][n] = (f32x4){0.f, 0.f, 0.f, 0.f};

    for (int kk = 0; kk < 256; kk += 32) {
        {
            int grow = row0 + xr;
            float4 v0 = make_float4(0.f, 0.f, 0.f, 0.f);
            float4 v1 = make_float4(0.f, 0.f, 0.f, 0.f);
            if (grow < N) {
                const float* p = x + (size_t)grow * 256 + kk + xq * 8;
                v0 = *(const float4*)(p);
                v1 = *(const float4*)(p + 4);
            }
            bf16x8 pk;
            pk[0] = (short)f2bf(v0.x); pk[1] = (short)f2bf(v0.y);
            pk[2] = (short)f2bf(v0.z); pk[3] = (short)f2bf(v0.w);
            pk[4] = (short)f2bf(v1.x); pk[5] = (short)f2bf(v1.y);
            pk[6] = (short)f2bf(v1.z); pk[7] = (short)f2bf(v1.w);
            *(bf16x8*)(&xs[xr][xq * 8]) = pk;
        }
        {
            bf16x8 w0, w1;
            #pragma unroll
            for (int j = 0; j < 8; ++j)
                w0[j] = (short)f2bf(wsrc[(size_t)(kk + wo * 16 + j) * 64]);
            #pragma unroll
            for (int j = 0; j < 8; ++j)
                w1[j] = (short)f2bf(wsrc[(size_t)(kk + wo * 16 + 8 + j) * 64]);
            *(bf16x8*)(&wsm[wc][wo * 16])     = w0;
            *(bf16x8*)(&wsm[wc][wo * 16 + 8]) = w1;
        }
        __syncthreads();

        int fr = lane & 15;
        int ko = (lane >> 4) * 8;
        bf16x8 a0 = *(const bf16x8*)(&xs[wm * 32 + fr][ko]);
        bf16x8 a1 = *(const bf16x8*)(&xs[wm * 32 + 16 + fr][ko]);
        bf16x8 b0 = *(const bf16x8*)(&wsm[wn * 64 + fr][ko]);
        bf16x8 b1 = *(const bf16x8*)(&wsm[wn * 64 + 16 + fr][ko]);
        bf16x8 b2 = *(const bf16x8*)(&wsm[wn * 64 + 32 + fr][ko]);
        bf16x8 b3 = *(const bf16x8*)(&wsm[wn * 64 + 48 + fr][ko]);

        acc[0][0] = __builtin_amdgcn_mfma_f32_16x16x32_bf16(a0, b0, acc[0][0], 0, 0, 0);
        acc[0][1] = __builtin_amdgcn_mfma_f32_16x16x32_bf16(a0, b1, acc[0][1], 0, 0, 0);
        acc[0][2] = __builtin_amdgcn_mfma_f32_16x16x32_bf16(a0, b2, acc[0][2], 0, 0, 0);
        acc[0][3] = __builtin_amdgcn_mfma_f32_16x16x32_bf16(a0, b3, acc[0][3], 0, 0, 0);
        acc[1][0] = __builtin_amdgcn_mfma_f32_16x16x32_bf16(a1, b0, acc[1][0], 0, 0, 0);
        acc[1][1] = __builtin_amdgcn_mfma_f32_16x16x32_bf16(a1, b1, acc[1][1], 0, 0, 0);
        acc[1][2] = __builtin_amdgcn_mfma_f32_16x16x32_bf16(a1, b2, acc[1][2], 0, 0, 0);
        acc[1][3] = __builtin_amdgcn_mfma_f32_16x16x32_bf16(a1, b3, acc[1][3], 0, 0, 0);
        __syncthreads();
    }

    // epilogue: C col = lane&15, row = (lane>>4)*4 + r
    // wn==0 -> self cols (fp32 y1l); wn==1 -> neighbor cols (bf16 y1r)
    int cn = lane & 15;
    int r4 = (lane >> 4) * 4;
    #pragma unroll
    for (int m = 0; m < 2; ++m) {
        #pragma unroll
        for (int r = 0; r < 4; ++r) {
            int row = row0 + wm * 32 + m * 16 + r4 + r;
            if (row < N) {
                if (wn == 0) {
                    float* yp = y1l + (size_t)row * 64 + cn;
                    yp[0]  = acc[m][0][r];
                    yp[16] = acc[m][1][r];
                    yp[32] = acc[m][2][r];
                    yp[48] = acc[m][3][r];
                } else {
                    unsigned short* yq = y1r + (size_t)row * 64 + cn;
                    yq[0]  = f2bf(acc[m][0][r]);
                    yq[16] = f2bf(acc[m][1][r]);
                    yq[32] = f2bf(acc[m][2][r]);
                    yq[48] = f2bf(acc[m][3][r]);
                }
            }
        }
    }
}

// ---- Fused: h_i = relu(y1l_i + mean(y1r[nbr]) + b1);  y2_i = h_i @ W2 ------
// Gather: packed bf16 rows (32 u32). Lanes 0-31 even edges, 32-63 odd edges;
// lane holds features {2*fl, 2*fl+1}. Pair-loop unrolled x4 -> 4 independent
// u32 loads = 8 edges in flight per lane. Combine shfl_xor(32) + redistribute.

__global__ __launch_bounds__(256) void k_fused2(const float* __restrict__ y1l,
                                                const unsigned int* __restrict__ y1ru,
                                                const int* __restrict__ csr,
                                                const int* __restrict__ off,
                                                const int* __restrict__ cnt,
                                                const float* __restrict__ b1,
                                                const float* __restrict__ W2l,
                                                const float* __restrict__ W2r,
                                                float* __restrict__ y2, int N) {
    __shared__ float wsm[64][80];    // [k][col], cols 0-39 = W2l, 40-79 = W2r
    __shared__ float hrow[4][64];    // per-wave h_i scratch
    int tid = threadIdx.x;
    #pragma unroll
    for (int it = 0; it < 5; ++it) {
        int idx = tid + it * 256;            // 0..1279
        int k = idx / 20;
        int cq = idx % 20;
        const float* s = (cq < 10) ? (W2l + (size_t)k * 40 + cq * 4)
                                   : (W2r + (size_t)k * 40 + (cq - 10) * 4);
        *(float4*)(&wsm[k][cq * 4]) = *(const float4*)s;
    }
    __syncthreads();

    int lane = tid & 63;
    int half = lane >> 5;            // 0: even edges, 1: odd edges
    int fl = lane & 31;              // feature-pair index (features 2fl, 2fl+1)
    int wv = tid >> 6;
    int wid = blockIdx.x * 4 + wv;
    int nw = gridDim.x * 4;
    float bl = b1[lane];
    int cl = (lane < 40) ? 2 * lane : 0;

    for (int i = wid; i < N; i += nw) {
        int deg = cnt[i];
        int start = off[i];
        float p0 = 0.f, p1 = 0.f;
        for (int base = 0; base < deg; base += 64) {
            int m = min(64, deg - base);
            int s = (lane < m) ? csr[start + base + lane] : 0;
            int pairs = (m + 1) >> 1;
            int t = 0;
            for (; t + 4 <= pairs; t += 4) {    // 8 edges per iter, 4 loads/lane
                int e0 = 2 * t + half;
                int e1 = e0 + 2;
                int e2 = e0 + 4;
                int e3 = e0 + 6;
                int s0 = __shfl(s, e0);
                int s1 = __shfl(s, e1);
                int s2 = __shfl(s, e2);
                int s3 = __shfl(s, e3);
                unsigned int u0 = y1ru[(size_t)s0 * 32 + fl];
                unsigned int u1 = y1ru[(size_t)s1 * 32 + fl];
                unsigned int u2 = y1ru[(size_t)s2 * 32 + fl];
                unsigned int u3 = y1ru[(size_t)s3 * 32 + fl];
                if (e0 < m) { p0 += bf2f(u0 & 0xffffu); p1 += bf2f(u0 >> 16); }
                if (e1 < m) { p0 += bf2f(u1 & 0xffffu); p1 += bf2f(u1 >> 16); }
                if (e2 < m) { p0 += bf2f(u2 & 0xffffu); p1 += bf2f(u2 >> 16); }
                if (e3 < m) { p0 += bf2f(u3 & 0xffffu); p1 += bf2f(u3 >> 16); }
            }
            for (; t < pairs; ++t) {
                int e0 = 2 * t + half;
                int s0 = __shfl(s, e0);
                unsigned int u0 = y1ru[(size_t)s0 * 32 + fl];
                if (e0 < m) { p0 += bf2f(u0 & 0xffffu); p1 += bf2f(u0 >> 16); }
            }
        }
        // combine even/odd halves, then redistribute to lane=feature
        p0 += __shfl_xor(p0, 32);
        p1 += __shfl_xor(p1, 32);
        float q0 = __shfl(p0, lane >> 1);
        float q1 = __shfl(p1, lane >> 1);
        float sum = (lane & 1) ? q1 : q0;
        float mean = sum / (float)max(deg, 1);
        float hv = fmaxf(y1l[(size_t)i * 64 + lane] + mean + bl, 0.f);

        hrow[wv][lane] = hv;
        float g0 = 0.f, g1 = 0.f;
        #pragma unroll
        for (int k4 = 0; k4 < 64; k4 += 4) {
            float4 hk = *(const float4*)(&hrow[wv][k4]);
            float2 w0 = *(const float2*)(&wsm[k4 + 0][cl]);
            float2 w1 = *(const float2*)(&wsm[k4 + 1][cl]);
            float2 w2 = *(const float2*)(&wsm[k4 + 2][cl]);
            float2 w3 = *(const float2*)(&wsm[k4 + 3][cl]);
            g0 += hk.x * w0.x + hk.y * w1.x + hk.z * w2.x + hk.w * w3.x;
            g1 += hk.x * w0.y + hk.y * w1.y + hk.z * w2.y + hk.w * w3.y;
        }
        if (lane < 40)
            *(float2*)(y2 + (size_t)i * 80 + cl) = make_float2(g0, g1);
    }
}

// ---------------- Agg2 + bias + softmax -------------------------------------

__global__ void k_agg2(const float* __restrict__ y2, const int* __restrict__ csr,
                       const int* __restrict__ off, const int* __restrict__ cnt,
                       const float* __restrict__ b2, float* __restrict__ out, int N) {
    int lane = threadIdx.x & 63;
    int wid = (blockIdx.x * blockDim.x + threadIdx.x) >> 6;
    int nw = (gridDim.x * blockDim.x) >> 6;
    for (int i = wid; i < N; i += nw) {
        int deg = cnt[i];
        int start = off[i];
        float a0 = 0.f, a1 = 0.f, a2 = 0.f, a3 = 0.f;
        bool act = (lane < 40);
        for (int base = 0; base < deg; base += 64) {
            int m = min(64, deg - base);
            int s = (lane < m) ? csr[start + base + lane] : 0;
            int j = 0;
            for (; j + 4 <= m; j += 4) {
                int s0 = __shfl(s, j), s1 = __shfl(s, j + 1);
                int s2 = __shfl(s, j + 2), s3 = __shfl(s, j + 3);
                if (act) {
                    a0 += y2[(size_t)s0 * 80 + 40 + lane];
                    a1 += y2[(size_t)s1 * 80 + 40 + lane];
                    a2 += y2[(size_t)s2 * 80 + 40 + lane];
                    a3 += y2[(size_t)s3 * 80 + 40 + lane];
                }
            }
            for (; j < m; ++j) {
                int sj = __shfl(s, j);
                if (act) a0 += y2[(size_t)sj * 80 + 40 + lane];
            }
        }
        float logit = -INFINITY;
        if (act) {
            float mean = (a0 + a1 + a2 + a3) / (float)max(deg, 1);
            logit = y2[(size_t)i * 80 + lane] + mean + b2[lane];
        }
        float mx = logit;
        #pragma unroll
        for (int o = 32; o > 0; o >>= 1) mx = fmaxf(mx, __shfl_xor(mx, o));
        float e = act ? expf(logit - mx) : 0.f;
        float se = e;
        #pragma unroll
        for (int o = 32; o > 0; o >>= 1) se += __shfl_xor(se, o);
        if (act) out[(size_t)i * 40 + lane] = e / se;
    }
}

// ---------------- launch ----------------------------------------------------

extern "C" void kernel_launch(void* const* d_in, const int* in_sizes, int n_in,
                              void* d_out, int out_size, void* d_ws, size_t ws_size,
                              hipStream_t stream) {
    const float* x   = (const float*)d_in[0];
    const int*   ei  = (const int*)d_in[1];
    const float* W1l = (const float*)d_in[2];
    const float* W1r = (const float*)d_in[3];
    const float* b1  = (const float*)d_in[4];
    const float* W2l = (const float*)d_in[5];
    const float* W2r = (const float*)d_in[6];
    const float* b2  = (const float*)d_in[7];
    float* out = (float*)d_out;

    int N = in_sizes[0] / 256;
    int E = in_sizes[1] / 2;
    const int* srcp = ei;
    const int* dstp = ei + E;

    char* w = (char*)d_ws;
    auto alloc = [&](size_t bytes) {
        char* p = w;
        w += (bytes + 255) & ~(size_t)255;
        return p;
    };
    int nb = (N + 255) / 256;
    int*            cnt    = (int*)alloc((size_t)N * 4);
    int*            off    = (int*)alloc((size_t)N * 4);
    int*            cursor = (int*)alloc((size_t)N * 4);
    int*            bsum   = (int*)alloc((size_t)nb * 4);
    int*            csr    = (int*)alloc((size_t)E * 4);
    float*          y1l    = (float*)alloc((size_t)N * 64 * 4);
    unsigned short* y1r    = (unsigned short*)alloc((size_t)N * 64 * 2);
    float*          y2     = (float*)alloc((size_t)N * 80 * 4);

    hipMemsetAsync(cnt, 0, (size_t)N * 4, stream);
    k_count<<<(E + 255) / 256, 256, 0, stream>>>(dstp, cnt, E);
    k_blocksum<<<nb, 256, 0, stream>>>(cnt, bsum, N);
    k_scanbsum<<<1, 512, 0, stream>>>(bsum, nb);
    k_scanfinal<<<nb, 256, 0, stream>>>(cnt, bsum, off, cursor, N);

    const int P = 4;
    int range = (N + P - 1) / P;               // 25K nodes -> 1.6MB csr window
    dim3 sgrid((E + 255) / 256, P);
    k_scatterp<<<sgrid, 256, 0, stream>>>(srcp, dstp, cursor, csr, E, range);

    k_gemm1<<<(N + 63) / 64, 256, 0, stream>>>(x, W1l, W1r, y1l, y1r, N);
    k_fused2<<<1792, 256, 0, stream>>>(y1l, (const unsigned int*)y1r, csr, off, cnt,
                                       b1, W2l, W2r, y2, N);
    k_agg2<<<2048, 256, 0, stream>>>(y2, csr, off, cnt, b2, out, N);
}

// Round 17
// 372.215 us; speedup vs baseline: 1.0389x; 1.0055x over previous
//
#include <hip/hip_runtime.h>
#include <hip/hip_bf16.h>
#include <math.h>

// ---------------------------------------------------------------------------
// GraphSAGE 2-layer forward.
// mean_j(x_j) @ W_r == mean_j(x_j @ W_r) -> project first, aggregate small.
// R17: fix R16's odd-m bounds bug. The 8-pair unrolled gather body was
// entered when t+8<=pairs, but for odd m (pairs=(m+1)>>1) half=1 lanes read
// edge e==m (one past end) -> shfl from a zero-filled lane -> node 0's row
// polluted odd-degree means (absmax 2.4e-2). Guarantee needs t+8 <= (m>>1);
// last odd pair falls into the already-guarded tail. Everything else
// identical to R16. Pre-commit stands: fused2 >= 105us -> revert to R13.
// ---------------------------------------------------------------------------

typedef __attribute__((ext_vector_type(8))) short bf16x8;
typedef __attribute__((ext_vector_type(4))) float f32x4;

static __device__ __forceinline__ unsigned short f2bf(float f) {
    unsigned int u = __builtin_bit_cast(unsigned int, f);
    unsigned int r = (u + 0x7FFFu + ((u >> 16) & 1u)) >> 16;   // RNE
    return (unsigned short)r;
}
static __device__ __forceinline__ float bf2f(unsigned int lo16) {
    unsigned int v = lo16 << 16;
    return __builtin_bit_cast(float, v);
}

// ---------------- CSR build ----------------

__global__ void k_count(const int* __restrict__ dst, int* __restrict__ cnt, int E) {
    int e = blockIdx.x * blockDim.x + threadIdx.x;
    if (e < E) atomicAdd(&cnt[dst[e]], 1);
}

__global__ void k_blocksum(const int* __restrict__ cnt, int* __restrict__ bsum, int N) {
    __shared__ int sm[256];
    int i = blockIdx.x * 256 + threadIdx.x;
    sm[threadIdx.x] = (i < N) ? cnt[i] : 0;
    __syncthreads();
    for (int s = 128; s > 0; s >>= 1) {
        if (threadIdx.x < s) sm[threadIdx.x] += sm[threadIdx.x + s];
        __syncthreads();
    }
    if (threadIdx.x == 0) bsum[blockIdx.x] = sm[0];
}

__global__ void k_scanbsum(int* __restrict__ bsum, int nb) {
    __shared__ int a[512], b[512];
    int t = threadIdx.x;
    int v = (t < nb) ? bsum[t] : 0;
    a[t] = v;
    __syncthreads();
    int* pin = a; int* pout = b;
    for (int o = 1; o < 512; o <<= 1) {
        pout[t] = (t >= o) ? pin[t] + pin[t - o] : pin[t];
        __syncthreads();
        int* tmp = pin; pin = pout; pout = tmp;
    }
    if (t < nb) bsum[t] = pin[t] - v;   // exclusive
}

__global__ void k_scanfinal(const int* __restrict__ cnt, const int* __restrict__ bsum,
                            int* __restrict__ off, int* __restrict__ cursor, int N) {
    __shared__ int a[256], b[256];
    int t = threadIdx.x;
    int i = blockIdx.x * 256 + t;
    int v = (i < N) ? cnt[i] : 0;
    a[t] = v;
    __syncthreads();
    int* pin = a; int* pout = b;
    for (int o = 1; o < 256; o <<= 1) {
        pout[t] = (t >= o) ? pin[t] + pin[t - o] : pin[t];
        __syncthreads();
        int* tmp = pin; pin = pout; pout = tmp;
    }
    if (i < N) {
        int ex = bsum[blockIdx.x] + pin[t] - v;
        off[i] = ex;
        cursor[i] = ex;
    }
}

// scatter, dst-range partitioned (pass = blockIdx.y): csr window L2-resident
__global__ void k_scatterp(const int* __restrict__ src, const int* __restrict__ dst,
                           int* __restrict__ cursor, int* __restrict__ csr,
                           int E, int range) {
    int e = blockIdx.x * blockDim.x + threadIdx.x;
    if (e < E) {
        int d = dst[e];
        int lo = blockIdx.y * range;
        if (d >= lo && d < lo + range) {
            int pos = atomicAdd(&cursor[d], 1);
            csr[pos] = src[e];
        }
    }
}

// ------- GEMM1 (MFMA): [y1l fp32 | y1r bf16] = bf16(x) @ bf16([W1_l|W1_r]) --

__global__ __launch_bounds__(256) void k_gemm1(const float* __restrict__ x,
                                               const float* __restrict__ Wl,
                                               const float* __restrict__ Wr,
                                               float* __restrict__ y1l,
                                               unsigned short* __restrict__ y1r, int N) {
    __shared__ unsigned short xs[64][40];     // bf16 [row][k]
    __shared__ unsigned short wsm[128][40];   // bf16 [col][k]
    int tid = threadIdx.x;
    int row0 = blockIdx.x * 64;
    int lane = tid & 63;
    int wid = tid >> 6;
    int wm = wid >> 1;
    int wn = wid & 1;

    int xr = tid >> 2;
    int xq = tid & 3;
    int wc = tid >> 1;
    int wo = tid & 1;
    const float* wsrc = (wc < 64) ? (Wl + wc) : (Wr + (wc - 64));

    f32x4 acc[2][4];
    #pragma unroll
    for (int m = 0; m < 2; ++m)
        #pragma unroll
        for (int n = 0; n < 4; ++n) acc[m][n] = (f32x4){0.f, 0.f, 0.f, 0.f};

    for (int kk = 0; kk < 256; kk += 32) {
        {
            int grow = row0 + xr;
            float4 v0 = make_float4(0.f, 0.f, 0.f, 0.f);
            float4 v1 = make_float4(0.f, 0.f, 0.f, 0.f);
            if (grow < N) {
                const float* p = x + (size_t)grow * 256 + kk + xq * 8;
                v0 = *(const float4*)(p);
                v1 = *(const float4*)(p + 4);
            }
            bf16x8 pk;
            pk[0] = (short)f2bf(v0.x); pk[1] = (short)f2bf(v0.y);
            pk[2] = (short)f2bf(v0.z); pk[3] = (short)f2bf(v0.w);
            pk[4] = (short)f2bf(v1.x); pk[5] = (short)f2bf(v1.y);
            pk[6] = (short)f2bf(v1.z); pk[7] = (short)f2bf(v1.w);
            *(bf16x8*)(&xs[xr][xq * 8]) = pk;
        }
        {
            bf16x8 w0, w1;
            #pragma unroll
            for (int j = 0; j < 8; ++j)
                w0[j] = (short)f2bf(wsrc[(size_t)(kk + wo * 16 + j) * 64]);
            #pragma unroll
            for (int j = 0; j < 8; ++j)
                w1[j] = (short)f2bf(wsrc[(size_t)(kk + wo * 16 + 8 + j) * 64]);
            *(bf16x8*)(&wsm[wc][wo * 16])     = w0;
            *(bf16x8*)(&wsm[wc][wo * 16 + 8]) = w1;
        }
        __syncthreads();

        int fr = lane & 15;
        int ko = (lane >> 4) * 8;
        bf16x8 a0 = *(const bf16x8*)(&xs[wm * 32 + fr][ko]);
        bf16x8 a1 = *(const bf16x8*)(&xs[wm * 32 + 16 + fr][ko]);
        bf16x8 b0 = *(const bf16x8*)(&wsm[wn * 64 + fr][ko]);
        bf16x8 b1 = *(const bf16x8*)(&wsm[wn * 64 + 16 + fr][ko]);
        bf16x8 b2 = *(const bf16x8*)(&wsm[wn * 64 + 32 + fr][ko]);
        bf16x8 b3 = *(const bf16x8*)(&wsm[wn * 64 + 48 + fr][ko]);

        acc[0][0] = __builtin_amdgcn_mfma_f32_16x16x32_bf16(a0, b0, acc[0][0], 0, 0, 0);
        acc[0][1] = __builtin_amdgcn_mfma_f32_16x16x32_bf16(a0, b1, acc[0][1], 0, 0, 0);
        acc[0][2] = __builtin_amdgcn_mfma_f32_16x16x32_bf16(a0, b2, acc[0][2], 0, 0, 0);
        acc[0][3] = __builtin_amdgcn_mfma_f32_16x16x32_bf16(a0, b3, acc[0][3], 0, 0, 0);
        acc[1][0] = __builtin_amdgcn_mfma_f32_16x16x32_bf16(a1, b0, acc[1][0], 0, 0, 0);
        acc[1][1] = __builtin_amdgcn_mfma_f32_16x16x32_bf16(a1, b1, acc[1][1], 0, 0, 0);
        acc[1][2] = __builtin_amdgcn_mfma_f32_16x16x32_bf16(a1, b2, acc[1][2], 0, 0, 0);
        acc[1][3] = __builtin_amdgcn_mfma_f32_16x16x32_bf16(a1, b3, acc[1][3], 0, 0, 0);
        __syncthreads();
    }

    // epilogue: C col = lane&15, row = (lane>>4)*4 + r
    // wn==0 -> self cols (fp32 y1l); wn==1 -> neighbor cols (bf16 y1r)
    int cn = lane & 15;
    int r4 = (lane >> 4) * 4;
    #pragma unroll
    for (int m = 0; m < 2; ++m) {
        #pragma unroll
        for (int r = 0; r < 4; ++r) {
            int row = row0 + wm * 32 + m * 16 + r4 + r;
            if (row < N) {
                if (wn == 0) {
                    float* yp = y1l + (size_t)row * 64 + cn;
                    yp[0]  = acc[m][0][r];
                    yp[16] = acc[m][1][r];
                    yp[32] = acc[m][2][r];
                    yp[48] = acc[m][3][r];
                } else {
                    unsigned short* yq = y1r + (size_t)row * 64 + cn;
                    yq[0]  = f2bf(acc[m][0][r]);
                    yq[16] = f2bf(acc[m][1][r]);
                    yq[32] = f2bf(acc[m][2][r]);
                    yq[48] = f2bf(acc[m][3][r]);
                }
            }
        }
    }
}

// ---- Fused: h_i = relu(y1l_i + mean(y1r[nbr]) + b1);  y2_i = h_i @ W2 ------
// Gather: packed bf16 rows (32 u32). Lanes 0-31 even edges, 32-63 odd edges.
// 8 independent u32 loads per lane per iter = 16 edges = 2KB/wave in flight.
// Unrolled body only when t+8 <= (m>>1): both halves in-bounds for any m.

__global__ __launch_bounds__(256) void k_fused2(const float* __restrict__ y1l,
                                                const unsigned int* __restrict__ y1ru,
                                                const int* __restrict__ csr,
                                                const int* __restrict__ off,
                                                const int* __restrict__ cnt,
                                                const float* __restrict__ b1,
                                                const float* __restrict__ W2l,
                                                const float* __restrict__ W2r,
                                                float* __restrict__ y2, int N) {
    __shared__ float wsm[64][80];    // [k][col], cols 0-39 = W2l, 40-79 = W2r
    __shared__ float hrow[4][64];    // per-wave h_i scratch
    int tid = threadIdx.x;
    #pragma unroll
    for (int it = 0; it < 5; ++it) {
        int idx = tid + it * 256;            // 0..1279
        int k = idx / 20;
        int cq = idx % 20;
        const float* s = (cq < 10) ? (W2l + (size_t)k * 40 + cq * 4)
                                   : (W2r + (size_t)k * 40 + (cq - 10) * 4);
        *(float4*)(&wsm[k][cq * 4]) = *(const float4*)s;
    }
    __syncthreads();

    int lane = tid & 63;
    int half = lane >> 5;            // 0: even edges, 1: odd edges
    int fl = lane & 31;              // feature-pair index (features 2fl, 2fl+1)
    int wv = tid >> 6;
    int wid = blockIdx.x * 4 + wv;
    int nw = gridDim.x * 4;
    float bl = b1[lane];
    int cl = (lane < 40) ? 2 * lane : 0;

    for (int i = wid; i < N; i += nw) {
        int deg = cnt[i];
        int start = off[i];
        float p0 = 0.f, p1 = 0.f;
        for (int base = 0; base < deg; base += 64) {
            int m = min(64, deg - base);
            int s = (lane < m) ? csr[start + base + lane] : 0;
            int pairs = (m + 1) >> 1;
            int full = m >> 1;       // pairs where BOTH even and odd edge exist
            int t = 0;
            for (; t + 8 <= full; t += 8) {     // 16 edges per iter, 8 loads/lane
                int sv[8];
                unsigned int uv[8];
                #pragma unroll
                for (int q = 0; q < 8; ++q) sv[q] = __shfl(s, 2 * (t + q) + half);
                #pragma unroll
                for (int q = 0; q < 8; ++q) uv[q] = y1ru[(size_t)sv[q] * 32 + fl];
                #pragma unroll
                for (int q = 0; q < 8; ++q) {
                    // e = 2*(t+q)+half <= 2*full-1 <= m-1 : in bounds for any m
                    p0 += bf2f(uv[q] & 0xffffu);
                    p1 += bf2f(uv[q] >> 16);
                }
            }
            for (; t + 2 <= pairs; t += 2) {
                int e0 = 2 * t + half;
                int e1 = e0 + 2;
                int s0 = __shfl(s, e0);
                int s1 = __shfl(s, e1);
                unsigned int u0 = y1ru[(size_t)s0 * 32 + fl];
                unsigned int u1 = y1ru[(size_t)s1 * 32 + fl];
                if (e0 < m) { p0 += bf2f(u0 & 0xffffu); p1 += bf2f(u0 >> 16); }
                if (e1 < m) { p0 += bf2f(u1 & 0xffffu); p1 += bf2f(u1 >> 16); }
            }
            for (; t < pairs; ++t) {
                int e0 = 2 * t + half;
                int s0 = __shfl(s, e0);
                unsigned int u0 = y1ru[(size_t)s0 * 32 + fl];
                if (e0 < m) { p0 += bf2f(u0 & 0xffffu); p1 += bf2f(u0 >> 16); }
            }
        }
        // combine even/odd halves, then redistribute to lane=feature
        p0 += __shfl_xor(p0, 32);
        p1 += __shfl_xor(p1, 32);
        float q0 = __shfl(p0, lane >> 1);
        float q1 = __shfl(p1, lane >> 1);
        float sum = (lane & 1) ? q1 : q0;
        float mean = sum / (float)max(deg, 1);
        float hv = fmaxf(y1l[(size_t)i * 64 + lane] + mean + bl, 0.f);

        hrow[wv][lane] = hv;
        float g0 = 0.f, g1 = 0.f;
        #pragma unroll
        for (int k4 = 0; k4 < 64; k4 += 4) {
            float4 hk = *(const float4*)(&hrow[wv][k4]);
            float2 w0 = *(const float2*)(&wsm[k4 + 0][cl]);
            float2 w1 = *(const float2*)(&wsm[k4 + 1][cl]);
            float2 w2 = *(const float2*)(&wsm[k4 + 2][cl]);
            float2 w3 = *(const float2*)(&wsm[k4 + 3][cl]);
            g0 += hk.x * w0.x + hk.y * w1.x + hk.z * w2.x + hk.w * w3.x;
            g1 += hk.x * w0.y + hk.y * w1.y + hk.z * w2.y + hk.w * w3.y;
        }
        if (lane < 40)
            *(float2*)(y2 + (size_t)i * 80 + cl) = make_float2(g0, g1);
    }
}

// ---------------- Agg2 + bias + softmax -------------------------------------

__global__ void k_agg2(const float* __restrict__ y2, const int* __restrict__ csr,
                       const int* __restrict__ off, const int* __restrict__ cnt,
                       const float* __restrict__ b2, float* __restrict__ out, int N) {
    int lane = threadIdx.x & 63;
    int wid = (blockIdx.x * blockDim.x + threadIdx.x) >> 6;
    int nw = (gridDim.x * blockDim.x) >> 6;
    for (int i = wid; i < N; i += nw) {
        int deg = cnt[i];
        int start = off[i];
        float a0 = 0.f, a1 = 0.f, a2 = 0.f, a3 = 0.f;
        bool act = (lane < 40);
        for (int base = 0; base < deg; base += 64) {
            int m = min(64, deg - base);
            int s = (lane < m) ? csr[start + base + lane] : 0;
            int j = 0;
            for (; j + 4 <= m; j += 4) {
                int s0 = __shfl(s, j), s1 = __shfl(s, j + 1);
                int s2 = __shfl(s, j + 2), s3 = __shfl(s, j + 3);
                if (act) {
                    a0 += y2[(size_t)s0 * 80 + 40 + lane];
                    a1 += y2[(size_t)s1 * 80 + 40 + lane];
                    a2 += y2[(size_t)s2 * 80 + 40 + lane];
                    a3 += y2[(size_t)s3 * 80 + 40 + lane];
                }
            }
            for (; j < m; ++j) {
                int sj = __shfl(s, j);
                if (act) a0 += y2[(size_t)sj * 80 + 40 + lane];
            }
        }
        float logit = -INFINITY;
        if (act) {
            float mean = (a0 + a1 + a2 + a3) / (float)max(deg, 1);
            logit = y2[(size_t)i * 80 + lane] + mean + b2[lane];
        }
        float mx = logit;
        #pragma unroll
        for (int o = 32; o > 0; o >>= 1) mx = fmaxf(mx, __shfl_xor(mx, o));
        float e = act ? expf(logit - mx) : 0.f;
        float se = e;
        #pragma unroll
        for (int o = 32; o > 0; o >>= 1) se += __shfl_xor(se, o);
        if (act) out[(size_t)i * 40 + lane] = e / se;
    }
}

// ---------------- launch ----------------------------------------------------

extern "C" void kernel_launch(void* const* d_in, const int* in_sizes, int n_in,
                              void* d_out, int out_size, void* d_ws, size_t ws_size,
                              hipStream_t stream) {
    const float* x   = (const float*)d_in[0];
    const int*   ei  = (const int*)d_in[1];
    const float* W1l = (const float*)d_in[2];
    const float* W1r = (const float*)d_in[3];
    const float* b1  = (const float*)d_in[4];
    const float* W2l = (const float*)d_in[5];
    const float* W2r = (const float*)d_in[6];
    const float* b2  = (const float*)d_in[7];
    float* out = (float*)d_out;

    int N = in_sizes[0] / 256;
    int E = in_sizes[1] / 2;
    const int* srcp = ei;
    const int* dstp = ei + E;

    char* w = (char*)d_ws;
    auto alloc = [&](size_t bytes) {
        char* p = w;
        w += (bytes + 255) & ~(size_t)255;
        return p;
    };
    int nb = (N + 255) / 256;
    int*            cnt    = (int*)alloc((size_t)N * 4);
    int*            off    = (int*)alloc((size_t)N * 4);
    int*            cursor = (int*)alloc((size_t)N * 4);
    int*            bsum   = (int*)alloc((size_t)nb * 4);
    int*            csr    = (int*)alloc((size_t)E * 4);
    float*          y1l    = (float*)alloc((size_t)N * 64 * 4);
    unsigned short* y1r    = (unsigned short*)alloc((size_t)N * 64 * 2);
    float*          y2     = (float*)alloc((size_t)N * 80 * 4);

    hipMemsetAsync(cnt, 0, (size_t)N * 4, stream);
    k_count<<<(E + 255) / 256, 256, 0, stream>>>(dstp, cnt, E);
    k_blocksum<<<nb, 256, 0, stream>>>(cnt, bsum, N);
    k_scanbsum<<<1, 512, 0, stream>>>(bsum, nb);
    k_scanfinal<<<nb, 256, 0, stream>>>(cnt, bsum, off, cursor, N);

    const int P = 4;
    int range = (N + P - 1) / P;               // 25K nodes -> 1.6MB csr window
    dim3 sgrid((E + 255) / 256, P);
    k_scatterp<<<sgrid, 256, 0, stream>>>(srcp, dstp, cursor, csr, E, range);

    k_gemm1<<<(N + 63) / 64, 256, 0, stream>>>(x, W1l, W1r, y1l, y1r, N);
    k_fused2<<<1792, 256, 0, stream>>>(y1l, (const unsigned int*)y1r, csr, off, cnt,
                                       b1, W2l, W2r, y2, N);
    k_agg2<<<2048, 256, 0, stream>>>(y2, csr, off, cnt, b2, out, N);
}

// Round 18
// 363.684 us; speedup vs baseline: 1.0633x; 1.0235x over previous
//
#include <hip/hip_runtime.h>
#include <hip/hip_bf16.h>
#include <math.h>

// ---------------------------------------------------------------------------
// GraphSAGE 2-layer forward.
// mean_j(x_j) @ W_r == mean_j(x_j @ W_r) -> project first, aggregate small.
// R18: pre-committed revert to R13 (session best, 361us). Gather track
// CLOSED after 5 probes: fp32 4-deep (102us) beats bf16-packed at equal
// bytes-in-flight (113), halved requests (124), and 2x bytes-in-flight
// (110). The irregular gather is at a per-edge service floor (~16G edge-
// gathers/s, 15% HBM, 36% VALU) insensitive to bytes/requests/concurrency.
// ---------------------------------------------------------------------------

typedef __attribute__((ext_vector_type(8))) short bf16x8;
typedef __attribute__((ext_vector_type(4))) float f32x4;

static __device__ __forceinline__ unsigned short f2bf(float f) {
    unsigned int u = __builtin_bit_cast(unsigned int, f);
    unsigned int r = (u + 0x7FFFu + ((u >> 16) & 1u)) >> 16;   // RNE
    return (unsigned short)r;
}

// ---------------- CSR build ----------------

__global__ void k_count(const int* __restrict__ dst, int* __restrict__ cnt, int E) {
    int e = blockIdx.x * blockDim.x + threadIdx.x;
    if (e < E) atomicAdd(&cnt[dst[e]], 1);
}

__global__ void k_blocksum(const int* __restrict__ cnt, int* __restrict__ bsum, int N) {
    __shared__ int sm[256];
    int i = blockIdx.x * 256 + threadIdx.x;
    sm[threadIdx.x] = (i < N) ? cnt[i] : 0;
    __syncthreads();
    for (int s = 128; s > 0; s >>= 1) {
        if (threadIdx.x < s) sm[threadIdx.x] += sm[threadIdx.x + s];
        __syncthreads();
    }
    if (threadIdx.x == 0) bsum[blockIdx.x] = sm[0];
}

__global__ void k_scanbsum(int* __restrict__ bsum, int nb) {
    __shared__ int a[512], b[512];
    int t = threadIdx.x;
    int v = (t < nb) ? bsum[t] : 0;
    a[t] = v;
    __syncthreads();
    int* pin = a; int* pout = b;
    for (int o = 1; o < 512; o <<= 1) {
        pout[t] = (t >= o) ? pin[t] + pin[t - o] : pin[t];
        __syncthreads();
        int* tmp = pin; pin = pout; pout = tmp;
    }
    if (t < nb) bsum[t] = pin[t] - v;   // exclusive
}

__global__ void k_scanfinal(const int* __restrict__ cnt, const int* __restrict__ bsum,
                            int* __restrict__ off, int* __restrict__ cursor, int N) {
    __shared__ int a[256], b[256];
    int t = threadIdx.x;
    int i = blockIdx.x * 256 + t;
    int v = (i < N) ? cnt[i] : 0;
    a[t] = v;
    __syncthreads();
    int* pin = a; int* pout = b;
    for (int o = 1; o < 256; o <<= 1) {
        pout[t] = (t >= o) ? pin[t] + pin[t - o] : pin[t];
        __syncthreads();
        int* tmp = pin; pin = pout; pout = tmp;
    }
    if (i < N) {
        int ex = bsum[blockIdx.x] + pin[t] - v;
        off[i] = ex;
        cursor[i] = ex;
    }
}

// scatter, dst-range partitioned: pass = blockIdx.y commits only edges whose
// dst lies in [pass*range, pass*range+range) -> csr window L2-resident.
__global__ void k_scatterp(const int* __restrict__ src, const int* __restrict__ dst,
                           int* __restrict__ cursor, int* __restrict__ csr,
                           int E, int range) {
    int e = blockIdx.x * blockDim.x + threadIdx.x;
    if (e < E) {
        int d = dst[e];
        int lo = blockIdx.y * range;
        if (d >= lo && d < lo + range) {
            int pos = atomicAdd(&cursor[d], 1);
            csr[pos] = src[e];
        }
    }
}

// ------- GEMM1 (MFMA): y1[N,128] = bf16(x)[N,256] @ bf16([W1_l | W1_r]) -----

__global__ __launch_bounds__(256) void k_gemm1(const float* __restrict__ x,
                                               const float* __restrict__ Wl,
                                               const float* __restrict__ Wr,
                                               float* __restrict__ y1, int N) {
    __shared__ unsigned short xs[64][40];     // bf16 [row][k]
    __shared__ unsigned short wsm[128][40];   // bf16 [col][k]
    int tid = threadIdx.x;
    int row0 = blockIdx.x * 64;
    int lane = tid & 63;
    int wid = tid >> 6;
    int wm = wid >> 1;
    int wn = wid & 1;

    int xr = tid >> 2;
    int xq = tid & 3;
    int wc = tid >> 1;
    int wo = tid & 1;
    const float* wsrc = (wc < 64) ? (Wl + wc) : (Wr + (wc - 64));

    f32x4 acc[2][4];
    #pragma unroll
    for (int m = 0; m < 2; ++m)
        #pragma unroll
        for (int n = 0; n < 4; ++n) acc[m][n] = (f32x4){0.f, 0.f, 0.f, 0.f};

    for (int kk = 0; kk < 256; kk += 32) {
        {
            int grow = row0 + xr;
            float4 v0 = make_float4(0.f, 0.f, 0.f, 0.f);
            float4 v1 = make_float4(0.f, 0.f, 0.f, 0.f);
            if (grow < N) {
                const float* p = x + (size_t)grow * 256 + kk + xq * 8;
                v0 = *(const float4*)(p);
                v1 = *(const float4*)(p + 4);
            }
            bf16x8 pk;
            pk[0] = (short)f2bf(v0.x); pk[1] = (short)f2bf(v0.y);
            pk[2] = (short)f2bf(v0.z); pk[3] = (short)f2bf(v0.w);
            pk[4] = (short)f2bf(v1.x); pk[5] = (short)f2bf(v1.y);
            pk[6] = (short)f2bf(v1.z); pk[7] = (short)f2bf(v1.w);
            *(bf16x8*)(&xs[xr][xq * 8]) = pk;
        }
        {
            bf16x8 w0, w1;
            #pragma unroll
            for (int j = 0; j < 8; ++j)
                w0[j] = (short)f2bf(wsrc[(size_t)(kk + wo * 16 + j) * 64]);
            #pragma unroll
            for (int j = 0; j < 8; ++j)
                w1[j] = (short)f2bf(wsrc[(size_t)(kk + wo * 16 + 8 + j) * 64]);
            *(bf16x8*)(&wsm[wc][wo * 16])     = w0;
            *(bf16x8*)(&wsm[wc][wo * 16 + 8]) = w1;
        }
        __syncthreads();

        int fr = lane & 15;
        int ko = (lane >> 4) * 8;
        bf16x8 a0 = *(const bf16x8*)(&xs[wm * 32 + fr][ko]);
        bf16x8 a1 = *(const bf16x8*)(&xs[wm * 32 + 16 + fr][ko]);
        bf16x8 b0 = *(const bf16x8*)(&wsm[wn * 64 + fr][ko]);
        bf16x8 b1 = *(const bf16x8*)(&wsm[wn * 64 + 16 + fr][ko]);
        bf16x8 b2 = *(const bf16x8*)(&wsm[wn * 64 + 32 + fr][ko]);
        bf16x8 b3 = *(const bf16x8*)(&wsm[wn * 64 + 48 + fr][ko]);

        acc[0][0] = __builtin_amdgcn_mfma_f32_16x16x32_bf16(a0, b0, acc[0][0], 0, 0, 0);
        acc[0][1] = __builtin_amdgcn_mfma_f32_16x16x32_bf16(a0, b1, acc[0][1], 0, 0, 0);
        acc[0][2] = __builtin_amdgcn_mfma_f32_16x16x32_bf16(a0, b2, acc[0][2], 0, 0, 0);
        acc[0][3] = __builtin_amdgcn_mfma_f32_16x16x32_bf16(a0, b3, acc[0][3], 0, 0, 0);
        acc[1][0] = __builtin_amdgcn_mfma_f32_16x16x32_bf16(a1, b0, acc[1][0], 0, 0, 0);
        acc[1][1] = __builtin_amdgcn_mfma_f32_16x16x32_bf16(a1, b1, acc[1][1], 0, 0, 0);
        acc[1][2] = __builtin_amdgcn_mfma_f32_16x16x32_bf16(a1, b2, acc[1][2], 0, 0, 0);
        acc[1][3] = __builtin_amdgcn_mfma_f32_16x16x32_bf16(a1, b3, acc[1][3], 0, 0, 0);
        __syncthreads();
    }

    int cn = lane & 15;
    int r4 = (lane >> 4) * 4;
    #pragma unroll
    for (int m = 0; m < 2; ++m) {
        #pragma unroll
        for (int r = 0; r < 4; ++r) {
            int row = row0 + wm * 32 + m * 16 + r4 + r;
            if (row < N) {
                float* yp = y1 + (size_t)row * 128 + wn * 64 + cn;
                yp[0]  = acc[m][0][r];
                yp[16] = acc[m][1][r];
                yp[32] = acc[m][2][r];
                yp[48] = acc[m][3][r];
            }
        }
    }
}

// ---- Fused: h_i = relu(xl_i + mean(xr[nbr]) + b1);  y2_i = h_i @ [W2l|W2r] ----

__global__ __launch_bounds__(256) void k_fused2(const float* __restrict__ y1,
                                                const int* __restrict__ csr,
                                                const int* __restrict__ off,
                                                const int* __restrict__ cnt,
                                                const float* __restrict__ b1,
                                                const float* __restrict__ W2l,
                                                const float* __restrict__ W2r,
                                                float* __restrict__ y2, int N) {
    __shared__ float wsm[64][80];    // [k][col], cols 0-39 = W2l, 40-79 = W2r
    __shared__ float hrow[4][64];    // per-wave h_i scratch
    int tid = threadIdx.x;
    #pragma unroll
    for (int it = 0; it < 5; ++it) {
        int idx = tid + it * 256;            // 0..1279
        int k = idx / 20;
        int cq = idx % 20;
        const float* s = (cq < 10) ? (W2l + (size_t)k * 40 + cq * 4)
                                   : (W2r + (size_t)k * 40 + (cq - 10) * 4);
        *(float4*)(&wsm[k][cq * 4]) = *(const float4*)s;
    }
    __syncthreads();

    int lane = tid & 63;
    int wv = tid >> 6;
    int wid = blockIdx.x * 4 + wv;
    int nw = gridDim.x * 4;
    float bl = b1[lane];
    int cl = (lane < 40) ? 2 * lane : 0;

    for (int i = wid; i < N; i += nw) {
        int deg = cnt[i];
        int start = off[i];
        float a0 = 0.f, a1 = 0.f, a2 = 0.f, a3 = 0.f;
        for (int base = 0; base < deg; base += 64) {
            int m = min(64, deg - base);
            int s = (lane < m) ? csr[start + base + lane] : 0;
            int j = 0;
            for (; j + 4 <= m; j += 4) {
                int s0 = __shfl(s, j), s1 = __shfl(s, j + 1);
                int s2 = __shfl(s, j + 2), s3 = __shfl(s, j + 3);
                a0 += y1[(size_t)s0 * 128 + 64 + lane];
                a1 += y1[(size_t)s1 * 128 + 64 + lane];
                a2 += y1[(size_t)s2 * 128 + 64 + lane];
                a3 += y1[(size_t)s3 * 128 + 64 + lane];
            }
            for (; j < m; ++j) {
                int sj = __shfl(s, j);
                a0 += y1[(size_t)sj * 128 + 64 + lane];
            }
        }
        float mean = (a0 + a1 + a2 + a3) / (float)max(deg, 1);
        float hv = fmaxf(y1[(size_t)i * 128 + lane] + mean + bl, 0.f);

        hrow[wv][lane] = hv;
        float p0 = 0.f, p1 = 0.f;
        #pragma unroll
        for (int k4 = 0; k4 < 64; k4 += 4) {
            float4 hk = *(const float4*)(&hrow[wv][k4]);
            float2 w0 = *(const float2*)(&wsm[k4 + 0][cl]);
            float2 w1 = *(const float2*)(&wsm[k4 + 1][cl]);
            float2 w2 = *(const float2*)(&wsm[k4 + 2][cl]);
            float2 w3 = *(const float2*)(&wsm[k4 + 3][cl]);
            p0 += hk.x * w0.x + hk.y * w1.x + hk.z * w2.x + hk.w * w3.x;
            p1 += hk.x * w0.y + hk.y * w1.y + hk.z * w2.y + hk.w * w3.y;
        }
        if (lane < 40)
            *(float2*)(y2 + (size_t)i * 80 + cl) = make_float2(p0, p1);
    }
}

// ---------------- Agg2 + bias + softmax -------------------------------------

__global__ void k_agg2(const float* __restrict__ y2, const int* __restrict__ csr,
                       const int* __restrict__ off, const int* __restrict__ cnt,
                       const float* __restrict__ b2, float* __restrict__ out, int N) {
    int lane = threadIdx.x & 63;
    int wid = (blockIdx.x * blockDim.x + threadIdx.x) >> 6;
    int nw = (gridDim.x * blockDim.x) >> 6;
    for (int i = wid; i < N; i += nw) {
        int deg = cnt[i];
        int start = off[i];
        float a0 = 0.f, a1 = 0.f, a2 = 0.f, a3 = 0.f;
        bool act = (lane < 40);
        for (int base = 0; base < deg; base += 64) {
            int m = min(64, deg - base);
            int s = (lane < m) ? csr[start + base + lane] : 0;
            int j = 0;
            for (; j + 4 <= m; j += 4) {
                int s0 = __shfl(s, j), s1 = __shfl(s, j + 1);
                int s2 = __shfl(s, j + 2), s3 = __shfl(s, j + 3);
                if (act) {
                    a0 += y2[(size_t)s0 * 80 + 40 + lane];
                    a1 += y2[(size_t)s1 * 80 + 40 + lane];
                    a2 += y2[(size_t)s2 * 80 + 40 + lane];
                    a3 += y2[(size_t)s3 * 80 + 40 + lane];
                }
            }
            for (; j < m; ++j) {
                int sj = __shfl(s, j);
                if (act) a0 += y2[(size_t)sj * 80 + 40 + lane];
            }
        }
        float logit = -INFINITY;
        if (act) {
            float mean = (a0 + a1 + a2 + a3) / (float)max(deg, 1);
            logit = y2[(size_t)i * 80 + lane] + mean + b2[lane];
        }
        float mx = logit;
        #pragma unroll
        for (int o = 32; o > 0; o >>= 1) mx = fmaxf(mx, __shfl_xor(mx, o));
        float e = act ? expf(logit - mx) : 0.f;
        float se = e;
        #pragma unroll
        for (int o = 32; o > 0; o >>= 1) se += __shfl_xor(se, o);
        if (act) out[(size_t)i * 40 + lane] = e / se;
    }
}

// ---------------- launch ----------------------------------------------------

extern "C" void kernel_launch(void* const* d_in, const int* in_sizes, int n_in,
                              void* d_out, int out_size, void* d_ws, size_t ws_size,
                              hipStream_t stream) {
    const float* x   = (const float*)d_in[0];
    const int*   ei  = (const int*)d_in[1];
    const float* W1l = (const float*)d_in[2];
    const float* W1r = (const float*)d_in[3];
    const float* b1  = (const float*)d_in[4];
    const float* W2l = (const float*)d_in[5];
    const float* W2r = (const float*)d_in[6];
    const float* b2  = (const float*)d_in[7];
    float* out = (float*)d_out;

    int N = in_sizes[0] / 256;
    int E = in_sizes[1] / 2;
    const int* srcp = ei;
    const int* dstp = ei + E;

    char* w = (char*)d_ws;
    auto alloc = [&](size_t bytes) {
        char* p = w;
        w += (bytes + 255) & ~(size_t)255;
        return p;
    };
    int nb = (N + 255) / 256;
    int*   cnt    = (int*)alloc((size_t)N * 4);
    int*   off    = (int*)alloc((size_t)N * 4);
    int*   cursor = (int*)alloc((size_t)N * 4);
    int*   bsum   = (int*)alloc((size_t)nb * 4);
    int*   csr    = (int*)alloc((size_t)E * 4);
    float* y1     = (float*)alloc((size_t)N * 128 * 4);
    float* y2     = (float*)alloc((size_t)N * 80 * 4);

    hipMemsetAsync(cnt, 0, (size_t)N * 4, stream);
    k_count<<<(E + 255) / 256, 256, 0, stream>>>(dstp, cnt, E);
    k_blocksum<<<nb, 256, 0, stream>>>(cnt, bsum, N);
    k_scanbsum<<<1, 512, 0, stream>>>(bsum, nb);
    k_scanfinal<<<nb, 256, 0, stream>>>(cnt, bsum, off, cursor, N);

    const int P = 4;
    int range = (N + P - 1) / P;               // 25K nodes -> 1.6MB csr window
    dim3 sgrid((E + 255) / 256, P);
    k_scatterp<<<sgrid, 256, 0, stream>>>(srcp, dstp, cursor, csr, E, range);

    k_gemm1<<<(N + 63) / 64, 256, 0, stream>>>(x, W1l, W1r, y1, N);
    k_fused2<<<1792, 256, 0, stream>>>(y1, csr, off, cnt, b1, W2l, W2r, y2, N);
    k_agg2<<<2048, 256, 0, stream>>>(y2, csr, off, cnt, b2, out, N);
}